// Round 16
// baseline (121.149 us; speedup 1.0000x reference)
//
#include <hip/hip_runtime.h>

#define CC 512
#define SS 4096
#define GELEMS 262144   // 64 ch * 4096 spatial per group

typedef __attribute__((ext_vector_type(8))) __bf16 bf16x8;
typedef __attribute__((ext_vector_type(4))) float f32x4;
typedef __attribute__((ext_vector_type(4))) unsigned short us4;
typedef __attribute__((ext_vector_type(8))) unsigned short us8;

__device__ __forceinline__ unsigned short f2bf(float f) {
  unsigned int u = __float_as_uint(f);
  u += 0x7fffu + ((u >> 16) & 1u);   // RNE
  return (unsigned short)(u >> 16);
}
__device__ __forceinline__ int qrow(int cv) { return ((cv >> 7) * 384) + 256 + (cv & 127); }

__device__ __forceinline__ void gl_lds16(const void* g, void* l) {
  __builtin_amdgcn_global_load_lds((const __attribute__((address_space(1))) unsigned int*)g,
                                   (__attribute__((address_space(3))) unsigned int*)l, 16, 0, 0);
}

// ======== K1 (fast): blocks <1024: BATCHED linear stats+convert, paired f32x4 NT loads,
//   us8 16B stores; blocks >=1024: Mw = proj_w @ qkv_w[r(.),:]  (64 blocks) ========
__global__ __launch_bounds__(256) void k_cvt_lin2(const float* __restrict__ x,
    const float* __restrict__ pw, const float* __restrict__ qw,
    unsigned short* __restrict__ xbf, float* __restrict__ part, float* __restrict__ mw) {
  __shared__ float red[8];
  __shared__ __align__(16) unsigned short Asb[64 * 32];
  __shared__ __align__(16) unsigned short Bsb[64 * 32];
  int t = threadIdx.x;
  int w = t >> 6, l = t & 63;
  if (blockIdx.x < 1024) {
    size_t base = (size_t)blockIdx.x * 32768;     // 32K floats per block (linear)
    const f32x4* p = (const f32x4*)(x + base);
    unsigned short* ob = xbf + base;
    float s = 0.f, ss = 0.f;
#pragma unroll 1
    for (int o = 0; o < 4; ++o) {
      f32x4 v[8];
#pragma unroll
      for (int k = 0; k < 4; ++k) {
        v[2 * k] = __builtin_nontemporal_load(&p[(size_t)(o * 4 + k) * 512 + t * 2]);
        v[2 * k + 1] = __builtin_nontemporal_load(&p[(size_t)(o * 4 + k) * 512 + t * 2 + 1]);
      }
#pragma unroll
      for (int k = 0; k < 8; ++k)
#pragma unroll
        for (int e = 0; e < 4; ++e) { s += v[k][e]; ss += v[k][e] * v[k][e]; }
#pragma unroll
      for (int k = 0; k < 4; ++k) {
        us8 q;
#pragma unroll
        for (int e = 0; e < 4; ++e) { q[e] = f2bf(v[2 * k][e]); q[4 + e] = f2bf(v[2 * k + 1][e]); }
        *(us8*)&ob[(size_t)(o * 4 + k) * 2048 + t * 8] = q;
      }
    }
#pragma unroll
    for (int off = 32; off; off >>= 1) { s += __shfl_down(s, off); ss += __shfl_down(ss, off); }
    if (l == 0) { red[w * 2] = s; red[w * 2 + 1] = ss; }
    __syncthreads();
    if (t == 0) {
      part[blockIdx.x * 2] = red[0] + red[2] + red[4] + red[6];
      part[blockIdx.x * 2 + 1] = red[1] + red[3] + red[5] + red[7];
    }
  } else {
    int bb = blockIdx.x - 1024;
    int bm = (bb >> 3) * 64;
    int bn = (bb & 7) * 64;
    int wm = (w >> 1) * 32, wn = (w & 1) * 32;
    int fr = l & 15, fk = (l >> 4) * 8;
    f32x4 acc[2][2] = {};
    for (int k0 = 0; k0 < 512; k0 += 32) {
#pragma unroll
      for (int i = 0; i < 2; ++i) {
        int e = i * 256 + t;
        int row = e >> 3, f4 = e & 7;
        float4 v = *(const float4*)&pw[(size_t)(bm + row) * 512 + k0 + f4 * 4];
        us4 pk; pk[0] = f2bf(v.x); pk[1] = f2bf(v.y); pk[2] = f2bf(v.z); pk[3] = f2bf(v.w);
        *(us4*)&Asb[row * 32 + f4 * 4] = pk;
      }
#pragma unroll
      for (int i = 0; i < 2; ++i) {
        int e = i * 256 + t;
        int row = e >> 4, f4 = e & 15;
        float4 v = *(const float4*)&qw[(size_t)qrow(k0 + row) * 512 + bn + f4 * 4];
        Bsb[(f4 * 4 + 0) * 32 + row] = f2bf(v.x);
        Bsb[(f4 * 4 + 1) * 32 + row] = f2bf(v.y);
        Bsb[(f4 * 4 + 2) * 32 + row] = f2bf(v.z);
        Bsb[(f4 * 4 + 3) * 32 + row] = f2bf(v.w);
      }
      __syncthreads();
      bf16x8 a[2], bfr[2];
#pragma unroll
      for (int i = 0; i < 2; ++i) a[i] = *(const bf16x8*)&Asb[(wm + i * 16 + fr) * 32 + fk];
#pragma unroll
      for (int j = 0; j < 2; ++j) bfr[j] = *(const bf16x8*)&Bsb[(wn + j * 16 + fr) * 32 + fk];
#pragma unroll
      for (int i = 0; i < 2; ++i)
#pragma unroll
        for (int j = 0; j < 2; ++j)
          acc[i][j] = __builtin_amdgcn_mfma_f32_16x16x32_bf16(a[i], bfr[j], acc[i][j], 0, 0, 0);
      __syncthreads();
    }
#pragma unroll
    for (int i = 0; i < 2; ++i)
#pragma unroll
      for (int j = 0; j < 2; ++j)
#pragma unroll
        for (int r = 0; r < 4; ++r) {
          int row = bm + wm + i * 16 + (l >> 4) * 4 + r;
          int col = bn + wn + j * 16 + (l & 15);
          mw[(size_t)row * 512 + col] = acc[i][j][r];
        }
  }
}

// ======== K2 (fast): blocks <2048: mwa = frag-ordered bf16(Mw*A+I); blocks >=2048: bias2 ========
__global__ __launch_bounds__(256) void k_prep(const float* __restrict__ part,
    const float* __restrict__ ng, const float* __restrict__ nb,
    const float* __restrict__ mw, const float* __restrict__ pw,
    const float* __restrict__ qb, const float* __restrict__ pb,
    unsigned short* __restrict__ mwa, float* __restrict__ bias2) {
  int t = threadIdx.x;
  __shared__ float S1[512], S2[512];
  __shared__ float ms[8], rs[8];
  int b = (blockIdx.x < 2048) ? (blockIdx.x >> 7) : ((blockIdx.x - 2048) >> 3);
  {
    int g = t >> 5, i = t & 31;
    const float* p = part + ((size_t)(b * 8 + g)) * 16;   // 8 pairs per (b,g)
    float S = 0.f, Q = 0.f;
    if (i < 8) { S = p[i * 2]; Q = p[i * 2 + 1]; }
#pragma unroll
    for (int off = 16; off; off >>= 1) { S += __shfl_down(S, off, 32); Q += __shfl_down(Q, off, 32); }
    if (i == 0) {
      float mean = S * (1.f / 262144.f);
      float var = Q * (1.f / 262144.f) - mean * mean;
      ms[g] = mean; rs[g] = rsqrtf(var + 1e-5f);
    }
  }
  __syncthreads();
  if (blockIdx.x < 2048) {
    int r4 = (blockIdx.x & 127) * 4;
#pragma unroll
    for (int q = 0; q < 2; ++q) { int c = t + q * 256; S1[c] = rs[c >> 6] * ng[c]; }
    __syncthreads();
    int c2 = r4 + (t >> 6), c = (t & 63) * 8;
    const float4* mr = (const float4*)&mw[(size_t)c2 * 512 + c];
    float4 m0 = mr[0], m1 = mr[1];
    const float4* ar = (const float4*)&S1[c];
    float4 a0 = ar[0], a1 = ar[1];
    float v[8] = {m0.x*a0.x, m0.y*a0.y, m0.z*a0.z, m0.w*a0.w,
                  m1.x*a1.x, m1.y*a1.y, m1.z*a1.z, m1.w*a1.w};
    if (c2 >= c && c2 < c + 8) v[c2 - c] += 1.0f;   // residual folded into diagonal
    us8 o;
#pragma unroll
    for (int j = 0; j < 8; ++j) o[j] = f2bf(v[j]);
    int wblk = c2 >> 6, i2 = (c2 >> 4) & 3, fr = c2 & 15;
    int step = c >> 5, fq = (c >> 3) & 3;
    size_t addr = ((((size_t)(b * 8 + wblk) * 4 + i2) * 16 + step) * 64 + (fq * 16 + fr)) * 8;
    *(us8*)&mwa[addr] = o;
  } else {
    int c2b = ((blockIdx.x - 2048) & 7) * 64;
    int w = t >> 6, l = t & 63;
#pragma unroll
    for (int q = 0; q < 2; ++q) {
      int c = t + q * 256;
      float A = rs[c >> 6] * ng[c];
      S1[c] = nb[c] - ms[c >> 6] * A;
      S2[c] = qb[qrow(c)];
    }
    __syncthreads();
    for (int it = 0; it < 16; ++it) {
      int c2 = c2b + w * 16 + it;
      const float4* pwr = (const float4*)&pw[(size_t)c2 * 512];
      const float4* mwr = (const float4*)&mw[(size_t)c2 * 512];
      float4 p0 = pwr[l * 2], p1 = pwr[l * 2 + 1];
      float4 m0 = mwr[l * 2], m1 = mwr[l * 2 + 1];
      const float4* qs = (const float4*)&S2[l * 8];
      const float4* bs = (const float4*)&S1[l * 8];
      float4 q0 = qs[0], q1 = qs[1], b0 = bs[0], b1 = bs[1];
      float acc = p0.x * q0.x + p0.y * q0.y + p0.z * q0.z + p0.w * q0.w
                + p1.x * q1.x + p1.y * q1.y + p1.z * q1.z + p1.w * q1.w
                + m0.x * b0.x + m0.y * b0.y + m0.z * b0.z + m0.w * b0.w
                + m1.x * b1.x + m1.y * b1.y + m1.z * b1.z + m1.w * b1.w;
#pragma unroll
      for (int off = 32; off; off >>= 1) acc += __shfl_down(acc, off);
      if (l == 0) bias2[b * 512 + c2] = acc + pb[c2];
    }
  }
}

// ======== K3 (fast): out = Mwb'@xbf + bias2 — in-kernel transpose from bf16 x,
//   8 x uint4 loads/thread + in-register 8x8 transpose + swizzled granule writes. ========
__global__ __launch_bounds__(512, 4) void k_fused10(const unsigned short* __restrict__ mwa,
    const unsigned short* __restrict__ xbf, const float* __restrict__ bias2,
    float* __restrict__ out) {
  __shared__ __align__(16) unsigned short Bt[32768];     // 64KB frag-order B; reused as scratch
  int bid0 = blockIdx.x;
  int bid = 1023 - ((bid0 & 7) * 128 + (bid0 >> 3));     // XCD swizzle + reverse
  int b = bid >> 6, st = bid & 63;
  int s0 = st * 64;
  int t = threadIdx.x, w = t >> 6, l = t & 63;
  int m0 = w * 64;
  int fr = l & 15, fq = l >> 4;
  const unsigned short* Ag = mwa + ((size_t)(b * 8 + w)) * 32768;   // [i][step][lane][8]

  // ---- stage: thread owns c-granule g (8 ch) x s-window sw (8 s) ----
  {
    int g = w * 8 + (l >> 3), sw = l & 7;
    const unsigned short* src = xbf + ((size_t)(b * 512 + g * 8)) * SS + s0 + sw * 8;
    uint4 r[8];
#pragma unroll
    for (int p = 0; p < 8; ++p) r[p] = *(const uint4*)(src + (size_t)p * SS);
    int kc = g >> 4, s8l = (g >> 2) & 3, fql = g & 3;
#pragma unroll
    for (int j = 0; j < 8; ++j) {
      uint4 ov;
      {
        unsigned int a0 = (j & 4) ? ((j & 2) ? r[0].w : r[0].z) : ((j & 2) ? r[0].y : r[0].x);
        unsigned int b0 = (j & 4) ? ((j & 2) ? r[1].w : r[1].z) : ((j & 2) ? r[1].y : r[1].x);
        unsigned int a1 = (j & 4) ? ((j & 2) ? r[2].w : r[2].z) : ((j & 2) ? r[2].y : r[2].x);
        unsigned int b1 = (j & 4) ? ((j & 2) ? r[3].w : r[3].z) : ((j & 2) ? r[3].y : r[3].x);
        unsigned int a2 = (j & 4) ? ((j & 2) ? r[4].w : r[4].z) : ((j & 2) ? r[4].y : r[4].x);
        unsigned int b2 = (j & 4) ? ((j & 2) ? r[5].w : r[5].z) : ((j & 2) ? r[5].y : r[5].x);
        unsigned int a3 = (j & 4) ? ((j & 2) ? r[6].w : r[6].z) : ((j & 2) ? r[6].y : r[6].x);
        unsigned int b3 = (j & 4) ? ((j & 2) ? r[7].w : r[7].z) : ((j & 2) ? r[7].y : r[7].x);
        if (j & 1) {
          ov.x = (b0 & 0xffff0000u) | (a0 >> 16);
          ov.y = (b1 & 0xffff0000u) | (a1 >> 16);
          ov.z = (b2 & 0xffff0000u) | (a2 >> 16);
          ov.w = (b3 & 0xffff0000u) | (a3 >> 16);
        } else {
          ov.x = (b0 << 16) | (a0 & 0xffffu);
          ov.y = (b1 << 16) | (a1 & 0xffffu);
          ov.z = (b2 << 16) | (a2 & 0xffffu);
          ov.w = (b3 << 16) | (a3 & 0xffffu);
        }
      }
      int s = sw * 8 + j;
      int jj = s >> 4, frr = (s & 15) ^ (fql << 1);      // bank-spread swizzle
      *(uint4*)&Bt[kc * 8192 + (s8l * 4 + jj) * 512 + (fql * 16 + frr) * 8] = ov;
    }
  }
  bf16x8 fa[2][4];
#pragma unroll
  for (int i = 0; i < 4; ++i)
    fa[0][i] = *(const bf16x8*)&Ag[(i * 16 + 0) * 512 + l * 8];
  __syncthreads();   // whole tile staged

  // ---- MFMA: 16 steps, no barriers (fb read applies same swizzle via lslot) ----
  int lslot = (fq * 16 + (fr ^ (fq << 1))) * 8;
  f32x4 acc[4][4] = {};
#pragma unroll
  for (int step = 0; step < 16; ++step) {
    const int cur2 = step & 1;
    if (step < 15) {
#pragma unroll
      for (int i = 0; i < 4; ++i)
        fa[cur2 ^ 1][i] = *(const bf16x8*)&Ag[(i * 16 + step + 1) * 512 + l * 8];
    }
    bf16x8 fb[4];
#pragma unroll
    for (int j = 0; j < 4; ++j)
      fb[j] = *(const bf16x8*)&Bt[(step >> 2) * 8192 + ((step & 3) * 4 + j) * 512 + lslot];
#pragma unroll
    for (int i = 0; i < 4; ++i)
#pragma unroll
      for (int j = 0; j < 4; ++j)
        acc[i][j] = __builtin_amdgcn_mfma_f32_16x16x32_bf16(fa[cur2][i], fb[j], acc[i][j], 0, 0, 0);
  }

  // ---- epilogue: bias add, per-wave LDS transpose, coalesced nt float4 stores ----
  float4 bi[4];
#pragma unroll
  for (int i = 0; i < 4; ++i)
    bi[i] = *(const float4*)&bias2[b * 512 + m0 + i * 16 + fq * 4];
  __syncthreads();               // all MFMAs done -> Bt reusable as scratch
  float* Ls = (float*)Bt;        // wave w owns floats [w*1024, +1024)
  float* ob = out + (size_t)b * 512 * SS + s0;
#pragma unroll
  for (int i = 0; i < 4; ++i) {
    float bir[4] = {bi[i].x, bi[i].y, bi[i].z, bi[i].w};
#pragma unroll
    for (int j = 0; j < 4; ++j)
#pragma unroll
      for (int r = 0; r < 4; ++r)
        Ls[w * 1024 + (fq * 4 + r) * 64 + (((j ^ fq) & 3) * 16 + fr)] = acc[i][j][r] + bir[r];
    asm volatile("s_waitcnt lgkmcnt(0)" ::: "memory");   // own-wave writes visible (lockstep wave)
    __builtin_amdgcn_sched_barrier(0);
#pragma unroll
    for (int q = 0; q < 4; ++q) {
      int row16 = q * 4 + (l >> 4);
      int colR = (l & 15) * 4;
      f32x4 v = *(const f32x4*)&Ls[w * 1024 + row16 * 64 + (colR ^ (q * 16))];
      __builtin_nontemporal_store(v, (f32x4*)&ob[(size_t)(m0 + i * 16 + row16) * SS + colR]);
    }
    asm volatile("s_waitcnt lgkmcnt(0)" ::: "memory");   // reads done before next i overwrites
  }
}

// ======== fallback path (ws too small): proven kernels ========
__global__ __launch_bounds__(256) void k_stats(const float* __restrict__ x, float* __restrict__ part) {
  int bid = blockIdx.x;
  int bg = bid >> 3, sp = bid & 7;
  const float4* p = (const float4*)(x + (size_t)bg * GELEMS + (size_t)sp * 32768);
  int t = threadIdx.x;
  float s = 0.f, ss = 0.f;
#pragma unroll
  for (int i = 0; i < 32; ++i) {
    float4 v = p[i * 256 + t];
    s += v.x + v.y + v.z + v.w;
    ss += v.x * v.x + v.y * v.y + v.z * v.z + v.w * v.w;
  }
#pragma unroll
  for (int off = 32; off; off >>= 1) { s += __shfl_down(s, off); ss += __shfl_down(ss, off); }
  __shared__ float red[8];
  int wid = t >> 6;
  if ((t & 63) == 0) { red[wid * 2] = s; red[wid * 2 + 1] = ss; }
  __syncthreads();
  if (t == 0) {
    part[bid * 2] = red[0] + red[2] + red[4] + red[6];
    part[bid * 2 + 1] = red[1] + red[3] + red[5] + red[7];
  }
}

__global__ __launch_bounds__(256) void k_mw(const float* __restrict__ pw, const float* __restrict__ qw,
                                            float* __restrict__ mw, unsigned short* __restrict__ mwbf) {
  __shared__ __align__(16) unsigned short Asb[64 * 32];
  __shared__ __align__(16) unsigned short Bsb[64 * 32];
  int t = threadIdx.x;
  int bm = (blockIdx.x >> 3) * 64;
  int bn = (blockIdx.x & 7) * 64;
  int w = t >> 6, l = t & 63;
  int wm = (w >> 1) * 32, wn = (w & 1) * 32;
  int fr = l & 15, fk = (l >> 4) * 8;
  f32x4 acc[2][2] = {};
  for (int k0 = 0; k0 < 512; k0 += 32) {
#pragma unroll
    for (int i = 0; i < 2; ++i) {
      int e = i * 256 + t;
      int row = e >> 3, f4 = e & 7;
      float4 v = *(const float4*)&pw[(size_t)(bm + row) * 512 + k0 + f4 * 4];
      us4 pk; pk[0] = f2bf(v.x); pk[1] = f2bf(v.y); pk[2] = f2bf(v.z); pk[3] = f2bf(v.w);
      *(us4*)&Asb[row * 32 + f4 * 4] = pk;
    }
#pragma unroll
    for (int i = 0; i < 2; ++i) {
      int e = i * 256 + t;
      int row = e >> 4, f4 = e & 15;
      float4 v = *(const float4*)&qw[(size_t)qrow(k0 + row) * 512 + bn + f4 * 4];
      Bsb[(f4 * 4 + 0) * 32 + row] = f2bf(v.x);
      Bsb[(f4 * 4 + 1) * 32 + row] = f2bf(v.y);
      Bsb[(f4 * 4 + 2) * 32 + row] = f2bf(v.z);
      Bsb[(f4 * 4 + 3) * 32 + row] = f2bf(v.w);
    }
    __syncthreads();
    bf16x8 a[2], bfr[2];
#pragma unroll
    for (int i = 0; i < 2; ++i) a[i] = *(const bf16x8*)&Asb[(wm + i * 16 + fr) * 32 + fk];
#pragma unroll
    for (int j = 0; j < 2; ++j) bfr[j] = *(const bf16x8*)&Bsb[(wn + j * 16 + fr) * 32 + fk];
#pragma unroll
    for (int i = 0; i < 2; ++i)
#pragma unroll
      for (int j = 0; j < 2; ++j)
        acc[i][j] = __builtin_amdgcn_mfma_f32_16x16x32_bf16(a[i], bfr[j], acc[i][j], 0, 0, 0);
    __syncthreads();
  }
#pragma unroll
  for (int i = 0; i < 2; ++i)
#pragma unroll
    for (int j = 0; j < 2; ++j)
#pragma unroll
      for (int r = 0; r < 4; ++r) {
        int row = bm + wm + i * 16 + (l >> 4) * 4 + r;
        int col = bn + wn + j * 16 + (l & 15);
        float v = acc[i][j][r];
        mw[(size_t)row * 512 + col] = v;
        mwbf[(size_t)row * 512 + col] = f2bf(v);
      }
}

__global__ __launch_bounds__(256) void k_fin(const float* __restrict__ part,
    const float* __restrict__ ng, const float* __restrict__ nb,
    float* __restrict__ afac, float* __restrict__ bcv, int np) {
  int b = blockIdx.x, t = threadIdx.x;
  __shared__ float mean_s[8], rstd_s[8];
  int g = t >> 5, i = t & 31;
  float S = 0.f, Q = 0.f;
  for (int k = i; k < np; k += 32) {
    S += part[((b * 8 + g) * np + k) * 2];
    Q += part[((b * 8 + g) * np + k) * 2 + 1];
  }
#pragma unroll
  for (int off = 16; off; off >>= 1) { S += __shfl_down(S, off, 32); Q += __shfl_down(Q, off, 32); }
  if (i == 0) {
    float mean = S * (1.f / 262144.f);
    float var = Q * (1.f / 262144.f) - mean * mean;
    mean_s[g] = mean;
    rstd_s[g] = rsqrtf(var + 1e-5f);
  }
  __syncthreads();
#pragma unroll
  for (int q = 0; q < 2; ++q) {
    int c = t + q * 256;
    int gg = c >> 6;
    float A = rstd_s[gg] * ng[c];
    afac[b * 512 + c] = A;
    bcv[b * 512 + c] = nb[c] - mean_s[gg] * A;
  }
}

__global__ __launch_bounds__(256) void k_bias2(const float* __restrict__ mw,
    const float* __restrict__ bcv, const float* __restrict__ pw,
    const float* __restrict__ qb, const float* __restrict__ pb, float* __restrict__ bias2) {
  int b = blockIdx.x >> 3, c2b = (blockIdx.x & 7) * 64;
  int t = threadIdx.x, w = t >> 6, l = t & 63;
  __shared__ float Bcs[512], Qbs[512];
  for (int i = t; i < 512; i += 256) { Bcs[i] = bcv[b * 512 + i]; Qbs[i] = qb[qrow(i)]; }
  __syncthreads();
  for (int it = 0; it < 16; ++it) {
    int c2 = c2b + w * 16 + it;
    const float4* pwr = (const float4*)&pw[(size_t)c2 * 512];
    const float4* mwr = (const float4*)&mw[(size_t)c2 * 512];
    float4 p0 = pwr[l * 2], p1 = pwr[l * 2 + 1];
    float4 m0 = mwr[l * 2], m1 = mwr[l * 2 + 1];
    const float4* qs = (const float4*)&Qbs[l * 8];
    const float4* bs = (const float4*)&Bcs[l * 8];
    float4 q0 = qs[0], q1 = qs[1], b0 = bs[0], b1 = bs[1];
    float acc = p0.x * q0.x + p0.y * q0.y + p0.z * q0.z + p0.w * q0.w
              + p1.x * q1.x + p1.y * q1.y + p1.z * q1.z + p1.w * q1.w
              + m0.x * b0.x + m0.y * b0.y + m0.z * b0.z + m0.w * b0.w
              + m1.x * b1.x + m1.y * b1.y + m1.z * b1.z + m1.w * b1.w;
#pragma unroll
    for (int off = 32; off; off >>= 1) acc += __shfl_down(acc, off);
    if (l == 0) bias2[b * 512 + c2] = acc + pb[c2];
  }
}

__global__ __launch_bounds__(256) void k_gemm_fb(const unsigned short* __restrict__ mwbf,
    const float* __restrict__ x, const float* __restrict__ afac,
    const float* __restrict__ bias2, float* __restrict__ out) {
  __shared__ __align__(16) unsigned short Ab[128 * 32];
  __shared__ __align__(16) unsigned short Bb[128 * 32];
  __shared__ float Afs[512];
  int bid0 = blockIdx.x;
  int bid = (bid0 & 7) * 256 + (bid0 >> 3);
  int b = bid >> 7, rem = bid & 127, nt = rem >> 2, mt = rem & 3;
  int m0 = mt * 128, s0 = nt * 128;
  int t = threadIdx.x, w = t >> 6, l = t & 63;
  int wm = (w >> 1) * 64, wn = (w & 1) * 64;
  const unsigned short* Ag = mwbf + (size_t)m0 * CC;
  int lr = l >> 2, lk = (l & 3) * 8;
  int fr = l & 15, fk = (l >> 4) * 8;
  for (int i = t; i < 512; i += 256) Afs[i] = afac[b * CC + i];
  __syncthreads();
  f32x4 acc[4][4] = {};
  for (int k0 = 0; k0 < CC; k0 += 32) {
#pragma unroll
    for (int q = 0; q < 2; ++q) {
      int row = w * 32 + q * 16;
      gl_lds16(Ag + (size_t)(row + lr) * CC + k0 + lk, &Ab[row * 32]);
    }
#pragma unroll
    for (int i2 = 0; i2 < 4; ++i2) {
      int e = i2 * 256 + t;
      int row = e >> 5, f4 = e & 31;
      float4 v = *(const float4*)&x[((size_t)(b * CC + k0 + row)) * SS + s0 + f4 * 4];
      float a = Afs[k0 + row];
      Bb[(f4 * 4 + 0) * 32 + row] = f2bf(v.x * a);
      Bb[(f4 * 4 + 1) * 32 + row] = f2bf(v.y * a);
      Bb[(f4 * 4 + 2) * 32 + row] = f2bf(v.z * a);
      Bb[(f4 * 4 + 3) * 32 + row] = f2bf(v.w * a);
    }
    __syncthreads();
    bf16x8 af[4], bfr[4];
#pragma unroll
    for (int i = 0; i < 4; ++i) af[i] = *(const bf16x8*)&Ab[(wm + i * 16 + fr) * 32 + fk];
#pragma unroll
    for (int j = 0; j < 4; ++j) bfr[j] = *(const bf16x8*)&Bb[(wn + j * 16 + fr) * 32 + fk];
#pragma unroll
    for (int i = 0; i < 4; ++i)
#pragma unroll
      for (int j = 0; j < 4; ++j)
        acc[i][j] = __builtin_amdgcn_mfma_f32_16x16x32_bf16(af[i], bfr[j], acc[i][j], 0, 0, 0);
    __syncthreads();
  }
  int c2b = m0 + wm, sb = s0 + wn;
  float bi[4][4];
#pragma unroll
  for (int i = 0; i < 4; ++i)
#pragma unroll
    for (int r = 0; r < 4; ++r)
      bi[i][r] = bias2[b * CC + c2b + i * 16 + (l >> 4) * 4 + r];
#pragma unroll
  for (int i = 0; i < 4; ++i)
#pragma unroll
    for (int j = 0; j < 4; ++j)
#pragma unroll
      for (int r = 0; r < 4; ++r) {
        int c2 = c2b + i * 16 + (l >> 4) * 4 + r;
        int s = sb + j * 16 + (l & 15);
        size_t oi = ((size_t)(b * CC + c2)) * SS + s;
        out[oi] = acc[i][j][r] + bi[i][r] + x[oi];
      }
}

extern "C" void kernel_launch(void* const* d_in, const int* in_sizes, int n_in,
                              void* d_out, int out_size, void* d_ws, size_t ws_size,
                              hipStream_t stream) {
  const float* x = (const float*)d_in[0];
  const float* ng = (const float*)d_in[1];
  const float* nb = (const float*)d_in[2];
  const float* qw = (const float*)d_in[3];
  const float* qb = (const float*)d_in[4];
  const float* pw = (const float*)d_in[5];
  const float* pb = (const float*)d_in[6];
  float* out = (float*)d_out;
  char* ws = (char*)d_ws;

  float* part = (float*)(ws + 0);                          //   8 KB
  float* afac = (float*)(ws + 65536);                      //  32 KB (fb only)
  float* bcv = (float*)(ws + 98304);                       //  32 KB (fb only)
  float* bias2 = (float*)(ws + 131072);                    //  32 KB
  float* mw = (float*)(ws + 163840);                       //   1 MB
  unsigned short* mwbf = (unsigned short*)(ws + 1212416);  // 512 KB (fb only)
  unsigned short* mwa = (unsigned short*)(ws + 1736704);   //   8 MB (frag-ordered, fast)
  unsigned short* xbf = (unsigned short*)(ws + 10125312);  //  64 MB bf16(x) -> end 77234176

  bool fast = ws_size >= 77234176ull;

  if (fast) {
    k_cvt_lin2<<<1088, 256, 0, stream>>>(x, pw, qw, xbf, part, mw);
    k_prep<<<2176, 256, 0, stream>>>(part, ng, nb, mw, pw, qb, pb, mwa, bias2);
    k_fused10<<<1024, 512, 0, stream>>>(mwa, xbf, bias2, out);
  } else {
    k_stats<<<1024, 256, 0, stream>>>(x, part);
    k_mw<<<64, 256, 0, stream>>>(pw, qw, mw, mwbf);
    k_fin<<<16, 256, 0, stream>>>(part, ng, nb, afac, bcv, 8);
    k_bias2<<<128, 256, 0, stream>>>(mw, bcv, pw, qb, pb, bias2);
    k_gemm_fb<<<2048, 256, 0, stream>>>(mwbf, x, afac, bias2, out);
  }
}

// Round 17
// 105.398 us; speedup vs baseline: 1.1494x; 1.1494x over previous
//
#include <hip/hip_runtime.h>

#define CC 512
#define SS 4096
#define GELEMS 262144   // 64 ch * 4096 spatial per group

typedef __attribute__((ext_vector_type(8))) __bf16 bf16x8;
typedef __attribute__((ext_vector_type(4))) float f32x4;
typedef __attribute__((ext_vector_type(4))) unsigned short us4;
typedef __attribute__((ext_vector_type(8))) unsigned short us8;

__device__ __forceinline__ unsigned short f2bf(float f) {
  unsigned int u = __float_as_uint(f);
  u += 0x7fffu + ((u >> 16) & 1u);   // RNE
  return (unsigned short)(u >> 16);
}
__device__ __forceinline__ int qrow(int cv) { return ((cv >> 7) * 384) + 256 + (cv & 127); }

__device__ __forceinline__ void gl_lds16(const void* g, void* l) {
  __builtin_amdgcn_global_load_lds((const __attribute__((address_space(1))) unsigned int*)g,
                                   (__attribute__((address_space(3))) unsigned int*)l, 16, 0, 0);
}

// ======== K1 (fast): blocks <512: BATCHED linear stats+convert (16-deep load batches,
//   one vmcnt drain per 32 VMEM ops); blocks >=512: Mw = proj_w @ qkv_w[r(.),:] ========
__global__ __launch_bounds__(256) void k_cvt_lin(const float* __restrict__ x,
    const float* __restrict__ pw, const float* __restrict__ qw,
    unsigned short* __restrict__ xbf, float* __restrict__ part, float* __restrict__ mw) {
  __shared__ float red[8];
  __shared__ __align__(16) unsigned short Asb[64 * 32];
  __shared__ __align__(16) unsigned short Bsb[64 * 32];
  int t = threadIdx.x;
  int w = t >> 6, l = t & 63;
  if (blockIdx.x < 512) {
    size_t base = (size_t)blockIdx.x * 65536;     // 64K floats per block (linear)
    const float4* p = (const float4*)(x + base);
    unsigned short* ob = xbf + base;
    float s = 0.f, ss = 0.f;
#pragma unroll 1
    for (int o = 0; o < 4; ++o) {
      float4 v[16];
#pragma unroll
      for (int k = 0; k < 16; ++k) v[k] = p[(o * 16 + k) * 256 + t];
#pragma unroll
      for (int k = 0; k < 16; ++k) {
        s += v[k].x + v[k].y + v[k].z + v[k].w;
        ss += v[k].x * v[k].x + v[k].y * v[k].y + v[k].z * v[k].z + v[k].w * v[k].w;
      }
#pragma unroll
      for (int k = 0; k < 16; ++k) {
        us4 q; q[0] = f2bf(v[k].x); q[1] = f2bf(v[k].y); q[2] = f2bf(v[k].z); q[3] = f2bf(v[k].w);
        *(us4*)&ob[((size_t)(o * 16 + k) * 256 + t) * 4] = q;
      }
    }
#pragma unroll
    for (int off = 32; off; off >>= 1) { s += __shfl_down(s, off); ss += __shfl_down(ss, off); }
    if (l == 0) { red[w * 2] = s; red[w * 2 + 1] = ss; }
    __syncthreads();
    if (t == 0) {
      part[blockIdx.x * 2] = red[0] + red[2] + red[4] + red[6];
      part[blockIdx.x * 2 + 1] = red[1] + red[3] + red[5] + red[7];
    }
  } else {
    int bb = blockIdx.x - 512;
    int bm = (bb >> 3) * 64;
    int bn = (bb & 7) * 64;
    int wm = (w >> 1) * 32, wn = (w & 1) * 32;
    int fr = l & 15, fk = (l >> 4) * 8;
    f32x4 acc[2][2] = {};
    for (int k0 = 0; k0 < 512; k0 += 32) {
#pragma unroll
      for (int i = 0; i < 2; ++i) {
        int e = i * 256 + t;
        int row = e >> 3, f4 = e & 7;
        float4 v = *(const float4*)&pw[(size_t)(bm + row) * 512 + k0 + f4 * 4];
        us4 pk; pk[0] = f2bf(v.x); pk[1] = f2bf(v.y); pk[2] = f2bf(v.z); pk[3] = f2bf(v.w);
        *(us4*)&Asb[row * 32 + f4 * 4] = pk;
      }
#pragma unroll
      for (int i = 0; i < 2; ++i) {
        int e = i * 256 + t;
        int row = e >> 4, f4 = e & 15;
        float4 v = *(const float4*)&qw[(size_t)qrow(k0 + row) * 512 + bn + f4 * 4];
        Bsb[(f4 * 4 + 0) * 32 + row] = f2bf(v.x);
        Bsb[(f4 * 4 + 1) * 32 + row] = f2bf(v.y);
        Bsb[(f4 * 4 + 2) * 32 + row] = f2bf(v.z);
        Bsb[(f4 * 4 + 3) * 32 + row] = f2bf(v.w);
      }
      __syncthreads();
      bf16x8 a[2], bfr[2];
#pragma unroll
      for (int i = 0; i < 2; ++i) a[i] = *(const bf16x8*)&Asb[(wm + i * 16 + fr) * 32 + fk];
#pragma unroll
      for (int j = 0; j < 2; ++j) bfr[j] = *(const bf16x8*)&Bsb[(wn + j * 16 + fr) * 32 + fk];
#pragma unroll
      for (int i = 0; i < 2; ++i)
#pragma unroll
        for (int j = 0; j < 2; ++j)
          acc[i][j] = __builtin_amdgcn_mfma_f32_16x16x32_bf16(a[i], bfr[j], acc[i][j], 0, 0, 0);
      __syncthreads();
    }
#pragma unroll
    for (int i = 0; i < 2; ++i)
#pragma unroll
      for (int j = 0; j < 2; ++j)
#pragma unroll
        for (int r = 0; r < 4; ++r) {
          int row = bm + wm + i * 16 + (l >> 4) * 4 + r;
          int col = bn + wn + j * 16 + (l & 15);
          mw[(size_t)row * 512 + col] = acc[i][j][r];
        }
  }
}

// ======== K2 (fast): blocks <2048: mwa = frag-ordered bf16(Mw*A+I); blocks >=2048: bias2 ========
__global__ __launch_bounds__(256) void k_prep(const float* __restrict__ part,
    const float* __restrict__ ng, const float* __restrict__ nb,
    const float* __restrict__ mw, const float* __restrict__ pw,
    const float* __restrict__ qb, const float* __restrict__ pb,
    unsigned short* __restrict__ mwa, float* __restrict__ bias2) {
  int t = threadIdx.x;
  __shared__ float S1[512], S2[512];
  __shared__ float ms[8], rs[8];
  int b = (blockIdx.x < 2048) ? (blockIdx.x >> 7) : ((blockIdx.x - 2048) >> 3);
  {
    int g = t >> 5, i = t & 31;
    const float* p = part + ((size_t)(b * 8 + g)) * 8;   // 4 pairs per (b,g)
    float S = 0.f, Q = 0.f;
    if (i < 4) { S = p[i * 2]; Q = p[i * 2 + 1]; }
#pragma unroll
    for (int off = 16; off; off >>= 1) { S += __shfl_down(S, off, 32); Q += __shfl_down(Q, off, 32); }
    if (i == 0) {
      float mean = S * (1.f / 262144.f);
      float var = Q * (1.f / 262144.f) - mean * mean;
      ms[g] = mean; rs[g] = rsqrtf(var + 1e-5f);
    }
  }
  __syncthreads();
  if (blockIdx.x < 2048) {
    int r4 = (blockIdx.x & 127) * 4;
#pragma unroll
    for (int q = 0; q < 2; ++q) { int c = t + q * 256; S1[c] = rs[c >> 6] * ng[c]; }
    __syncthreads();
    int c2 = r4 + (t >> 6), c = (t & 63) * 8;
    const float4* mr = (const float4*)&mw[(size_t)c2 * 512 + c];
    float4 m0 = mr[0], m1 = mr[1];
    const float4* ar = (const float4*)&S1[c];
    float4 a0 = ar[0], a1 = ar[1];
    float v[8] = {m0.x*a0.x, m0.y*a0.y, m0.z*a0.z, m0.w*a0.w,
                  m1.x*a1.x, m1.y*a1.y, m1.z*a1.z, m1.w*a1.w};
    if (c2 >= c && c2 < c + 8) v[c2 - c] += 1.0f;   // residual folded into diagonal
    us8 o;
#pragma unroll
    for (int j = 0; j < 8; ++j) o[j] = f2bf(v[j]);
    int wblk = c2 >> 6, i2 = (c2 >> 4) & 3, fr = c2 & 15;
    int step = c >> 5, fq = (c >> 3) & 3;
    size_t addr = ((((size_t)(b * 8 + wblk) * 4 + i2) * 16 + step) * 64 + (fq * 16 + fr)) * 8;
    *(us8*)&mwa[addr] = o;
  } else {
    int c2b = ((blockIdx.x - 2048) & 7) * 64;
    int w = t >> 6, l = t & 63;
#pragma unroll
    for (int q = 0; q < 2; ++q) {
      int c = t + q * 256;
      float A = rs[c >> 6] * ng[c];
      S1[c] = nb[c] - ms[c >> 6] * A;
      S2[c] = qb[qrow(c)];
    }
    __syncthreads();
    for (int it = 0; it < 16; ++it) {
      int c2 = c2b + w * 16 + it;
      const float4* pwr = (const float4*)&pw[(size_t)c2 * 512];
      const float4* mwr = (const float4*)&mw[(size_t)c2 * 512];
      float4 p0 = pwr[l * 2], p1 = pwr[l * 2 + 1];
      float4 m0 = mwr[l * 2], m1 = mwr[l * 2 + 1];
      const float4* qs = (const float4*)&S2[l * 8];
      const float4* bs = (const float4*)&S1[l * 8];
      float4 q0 = qs[0], q1 = qs[1], b0 = bs[0], b1 = bs[1];
      float acc = p0.x * q0.x + p0.y * q0.y + p0.z * q0.z + p0.w * q0.w
                + p1.x * q1.x + p1.y * q1.y + p1.z * q1.z + p1.w * q1.w
                + m0.x * b0.x + m0.y * b0.y + m0.z * b0.z + m0.w * b0.w
                + m1.x * b1.x + m1.y * b1.y + m1.z * b1.z + m1.w * b1.w;
#pragma unroll
      for (int off = 32; off; off >>= 1) acc += __shfl_down(acc, off);
      if (l == 0) bias2[b * 512 + c2] = acc + pb[c2];
    }
  }
}

// ======== K3 (fast): out = Mwb'@xbf + bias2 — in-kernel transpose from bf16 x,
//   8 x uint4 loads/thread + in-register 8x8 transpose + swizzled granule writes. ========
__global__ __launch_bounds__(512, 4) void k_fused10(const unsigned short* __restrict__ mwa,
    const unsigned short* __restrict__ xbf, const float* __restrict__ bias2,
    float* __restrict__ out) {
  __shared__ __align__(16) unsigned short Bt[32768];     // 64KB frag-order B; reused as scratch
  int bid0 = blockIdx.x;
  int bid = 1023 - ((bid0 & 7) * 128 + (bid0 >> 3));     // XCD swizzle + reverse
  int b = bid >> 6, st = bid & 63;
  int s0 = st * 64;
  int t = threadIdx.x, w = t >> 6, l = t & 63;
  int m0 = w * 64;
  int fr = l & 15, fq = l >> 4;
  const unsigned short* Ag = mwa + ((size_t)(b * 8 + w)) * 32768;   // [i][step][lane][8]

  // ---- stage: thread owns c-granule g (8 ch) x s-window sw (8 s) ----
  {
    int g = w * 8 + (l >> 3), sw = l & 7;
    const unsigned short* src = xbf + ((size_t)(b * 512 + g * 8)) * SS + s0 + sw * 8;
    uint4 r[8];
#pragma unroll
    for (int p = 0; p < 8; ++p) r[p] = *(const uint4*)(src + (size_t)p * SS);
    int kc = g >> 4, s8l = (g >> 2) & 3, fql = g & 3;
#pragma unroll
    for (int j = 0; j < 8; ++j) {
      uint4 ov;
      {
        unsigned int a0 = (j & 4) ? ((j & 2) ? r[0].w : r[0].z) : ((j & 2) ? r[0].y : r[0].x);
        unsigned int b0 = (j & 4) ? ((j & 2) ? r[1].w : r[1].z) : ((j & 2) ? r[1].y : r[1].x);
        unsigned int a1 = (j & 4) ? ((j & 2) ? r[2].w : r[2].z) : ((j & 2) ? r[2].y : r[2].x);
        unsigned int b1 = (j & 4) ? ((j & 2) ? r[3].w : r[3].z) : ((j & 2) ? r[3].y : r[3].x);
        unsigned int a2 = (j & 4) ? ((j & 2) ? r[4].w : r[4].z) : ((j & 2) ? r[4].y : r[4].x);
        unsigned int b2 = (j & 4) ? ((j & 2) ? r[5].w : r[5].z) : ((j & 2) ? r[5].y : r[5].x);
        unsigned int a3 = (j & 4) ? ((j & 2) ? r[6].w : r[6].z) : ((j & 2) ? r[6].y : r[6].x);
        unsigned int b3 = (j & 4) ? ((j & 2) ? r[7].w : r[7].z) : ((j & 2) ? r[7].y : r[7].x);
        if (j & 1) {
          ov.x = (b0 & 0xffff0000u) | (a0 >> 16);
          ov.y = (b1 & 0xffff0000u) | (a1 >> 16);
          ov.z = (b2 & 0xffff0000u) | (a2 >> 16);
          ov.w = (b3 & 0xffff0000u) | (a3 >> 16);
        } else {
          ov.x = (b0 << 16) | (a0 & 0xffffu);
          ov.y = (b1 << 16) | (a1 & 0xffffu);
          ov.z = (b2 << 16) | (a2 & 0xffffu);
          ov.w = (b3 << 16) | (a3 & 0xffffu);
        }
      }
      int s = sw * 8 + j;
      int jj = s >> 4, frr = (s & 15) ^ (fql << 1);      // bank-spread swizzle
      *(uint4*)&Bt[kc * 8192 + (s8l * 4 + jj) * 512 + (fql * 16 + frr) * 8] = ov;
    }
  }
  bf16x8 fa[2][4];
#pragma unroll
  for (int i = 0; i < 4; ++i)
    fa[0][i] = *(const bf16x8*)&Ag[(i * 16 + 0) * 512 + l * 8];
  __syncthreads();   // whole tile staged

  // ---- MFMA: 16 steps, no barriers (fb read applies same swizzle via lslot) ----
  int lslot = (fq * 16 + (fr ^ (fq << 1))) * 8;
  f32x4 acc[4][4] = {};
#pragma unroll
  for (int step = 0; step < 16; ++step) {
    const int cur2 = step & 1;
    if (step < 15) {
#pragma unroll
      for (int i = 0; i < 4; ++i)
        fa[cur2 ^ 1][i] = *(const bf16x8*)&Ag[(i * 16 + step + 1) * 512 + l * 8];
    }
    bf16x8 fb[4];
#pragma unroll
    for (int j = 0; j < 4; ++j)
      fb[j] = *(const bf16x8*)&Bt[(step >> 2) * 8192 + ((step & 3) * 4 + j) * 512 + lslot];
#pragma unroll
    for (int i = 0; i < 4; ++i)
#pragma unroll
      for (int j = 0; j < 4; ++j)
        acc[i][j] = __builtin_amdgcn_mfma_f32_16x16x32_bf16(fa[cur2][i], fb[j], acc[i][j], 0, 0, 0);
  }

  // ---- epilogue: bias add, per-wave LDS transpose, coalesced nt float4 stores ----
  float4 bi[4];
#pragma unroll
  for (int i = 0; i < 4; ++i)
    bi[i] = *(const float4*)&bias2[b * 512 + m0 + i * 16 + fq * 4];
  __syncthreads();               // all MFMAs done -> Bt reusable as scratch
  float* Ls = (float*)Bt;        // wave w owns floats [w*1024, +1024)
  float* ob = out + (size_t)b * 512 * SS + s0;
#pragma unroll
  for (int i = 0; i < 4; ++i) {
    float bir[4] = {bi[i].x, bi[i].y, bi[i].z, bi[i].w};
#pragma unroll
    for (int j = 0; j < 4; ++j)
#pragma unroll
      for (int r = 0; r < 4; ++r)
        Ls[w * 1024 + (fq * 4 + r) * 64 + (((j ^ fq) & 3) * 16 + fr)] = acc[i][j][r] + bir[r];
    asm volatile("s_waitcnt lgkmcnt(0)" ::: "memory");   // own-wave writes visible (lockstep wave)
    __builtin_amdgcn_sched_barrier(0);
#pragma unroll
    for (int q = 0; q < 4; ++q) {
      int row16 = q * 4 + (l >> 4);
      int colR = (l & 15) * 4;
      f32x4 v = *(const f32x4*)&Ls[w * 1024 + row16 * 64 + (colR ^ (q * 16))];
      __builtin_nontemporal_store(v, (f32x4*)&ob[(size_t)(m0 + i * 16 + row16) * SS + colR]);
    }
    asm volatile("s_waitcnt lgkmcnt(0)" ::: "memory");   // reads done before next i overwrites
  }
}

// ======== fallback path (ws too small): proven kernels ========
__global__ __launch_bounds__(256) void k_stats(const float* __restrict__ x, float* __restrict__ part) {
  int bid = blockIdx.x;
  int bg = bid >> 3, sp = bid & 7;
  const float4* p = (const float4*)(x + (size_t)bg * GELEMS + (size_t)sp * 32768);
  int t = threadIdx.x;
  float s = 0.f, ss = 0.f;
#pragma unroll
  for (int i = 0; i < 32; ++i) {
    float4 v = p[i * 256 + t];
    s += v.x + v.y + v.z + v.w;
    ss += v.x * v.x + v.y * v.y + v.z * v.z + v.w * v.w;
  }
#pragma unroll
  for (int off = 32; off; off >>= 1) { s += __shfl_down(s, off); ss += __shfl_down(ss, off); }
  __shared__ float red[8];
  int wid = t >> 6;
  if ((t & 63) == 0) { red[wid * 2] = s; red[wid * 2 + 1] = ss; }
  __syncthreads();
  if (t == 0) {
    part[bid * 2] = red[0] + red[2] + red[4] + red[6];
    part[bid * 2 + 1] = red[1] + red[3] + red[5] + red[7];
  }
}

__global__ __launch_bounds__(256) void k_mw(const float* __restrict__ pw, const float* __restrict__ qw,
                                            float* __restrict__ mw, unsigned short* __restrict__ mwbf) {
  __shared__ __align__(16) unsigned short Asb[64 * 32];
  __shared__ __align__(16) unsigned short Bsb[64 * 32];
  int t = threadIdx.x;
  int bm = (blockIdx.x >> 3) * 64;
  int bn = (blockIdx.x & 7) * 64;
  int w = t >> 6, l = t & 63;
  int wm = (w >> 1) * 32, wn = (w & 1) * 32;
  int fr = l & 15, fk = (l >> 4) * 8;
  f32x4 acc[2][2] = {};
  for (int k0 = 0; k0 < 512; k0 += 32) {
#pragma unroll
    for (int i = 0; i < 2; ++i) {
      int e = i * 256 + t;
      int row = e >> 3, f4 = e & 7;
      float4 v = *(const float4*)&pw[(size_t)(bm + row) * 512 + k0 + f4 * 4];
      us4 pk; pk[0] = f2bf(v.x); pk[1] = f2bf(v.y); pk[2] = f2bf(v.z); pk[3] = f2bf(v.w);
      *(us4*)&Asb[row * 32 + f4 * 4] = pk;
    }
#pragma unroll
    for (int i = 0; i < 2; ++i) {
      int e = i * 256 + t;
      int row = e >> 4, f4 = e & 15;
      float4 v = *(const float4*)&qw[(size_t)qrow(k0 + row) * 512 + bn + f4 * 4];
      Bsb[(f4 * 4 + 0) * 32 + row] = f2bf(v.x);
      Bsb[(f4 * 4 + 1) * 32 + row] = f2bf(v.y);
      Bsb[(f4 * 4 + 2) * 32 + row] = f2bf(v.z);
      Bsb[(f4 * 4 + 3) * 32 + row] = f2bf(v.w);
    }
    __syncthreads();
    bf16x8 a[2], bfr[2];
#pragma unroll
    for (int i = 0; i < 2; ++i) a[i] = *(const bf16x8*)&Asb[(wm + i * 16 + fr) * 32 + fk];
#pragma unroll
    for (int j = 0; j < 2; ++j) bfr[j] = *(const bf16x8*)&Bsb[(wn + j * 16 + fr) * 32 + fk];
#pragma unroll
    for (int i = 0; i < 2; ++i)
#pragma unroll
      for (int j = 0; j < 2; ++j)
        acc[i][j] = __builtin_amdgcn_mfma_f32_16x16x32_bf16(a[i], bfr[j], acc[i][j], 0, 0, 0);
    __syncthreads();
  }
#pragma unroll
  for (int i = 0; i < 2; ++i)
#pragma unroll
    for (int j = 0; j < 2; ++j)
#pragma unroll
      for (int r = 0; r < 4; ++r) {
        int row = bm + wm + i * 16 + (l >> 4) * 4 + r;
        int col = bn + wn + j * 16 + (l & 15);
        float v = acc[i][j][r];
        mw[(size_t)row * 512 + col] = v;
        mwbf[(size_t)row * 512 + col] = f2bf(v);
      }
}

__global__ __launch_bounds__(256) void k_fin(const float* __restrict__ part,
    const float* __restrict__ ng, const float* __restrict__ nb,
    float* __restrict__ afac, float* __restrict__ bcv, int np) {
  int b = blockIdx.x, t = threadIdx.x;
  __shared__ float mean_s[8], rstd_s[8];
  int g = t >> 5, i = t & 31;
  float S = 0.f, Q = 0.f;
  for (int k = i; k < np; k += 32) {
    S += part[((b * 8 + g) * np + k) * 2];
    Q += part[((b * 8 + g) * np + k) * 2 + 1];
  }
#pragma unroll
  for (int off = 16; off; off >>= 1) { S += __shfl_down(S, off, 32); Q += __shfl_down(Q, off, 32); }
  if (i == 0) {
    float mean = S * (1.f / 262144.f);
    float var = Q * (1.f / 262144.f) - mean * mean;
    mean_s[g] = mean;
    rstd_s[g] = rsqrtf(var + 1e-5f);
  }
  __syncthreads();
#pragma unroll
  for (int q = 0; q < 2; ++q) {
    int c = t + q * 256;
    int gg = c >> 6;
    float A = rstd_s[gg] * ng[c];
    afac[b * 512 + c] = A;
    bcv[b * 512 + c] = nb[c] - mean_s[gg] * A;
  }
}

__global__ __launch_bounds__(256) void k_bias2(const float* __restrict__ mw,
    const float* __restrict__ bcv, const float* __restrict__ pw,
    const float* __restrict__ qb, const float* __restrict__ pb, float* __restrict__ bias2) {
  int b = blockIdx.x >> 3, c2b = (blockIdx.x & 7) * 64;
  int t = threadIdx.x, w = t >> 6, l = t & 63;
  __shared__ float Bcs[512], Qbs[512];
  for (int i = t; i < 512; i += 256) { Bcs[i] = bcv[b * 512 + i]; Qbs[i] = qb[qrow(i)]; }
  __syncthreads();
  for (int it = 0; it < 16; ++it) {
    int c2 = c2b + w * 16 + it;
    const float4* pwr = (const float4*)&pw[(size_t)c2 * 512];
    const float4* mwr = (const float4*)&mw[(size_t)c2 * 512];
    float4 p0 = pwr[l * 2], p1 = pwr[l * 2 + 1];
    float4 m0 = mwr[l * 2], m1 = mwr[l * 2 + 1];
    const float4* qs = (const float4*)&Qbs[l * 8];
    const float4* bs = (const float4*)&Bcs[l * 8];
    float4 q0 = qs[0], q1 = qs[1], b0 = bs[0], b1 = bs[1];
    float acc = p0.x * q0.x + p0.y * q0.y + p0.z * q0.z + p0.w * q0.w
              + p1.x * q1.x + p1.y * q1.y + p1.z * q1.z + p1.w * q1.w
              + m0.x * b0.x + m0.y * b0.y + m0.z * b0.z + m0.w * b0.w
              + m1.x * b1.x + m1.y * b1.y + m1.z * b1.z + m1.w * b1.w;
#pragma unroll
    for (int off = 32; off; off >>= 1) acc += __shfl_down(acc, off);
    if (l == 0) bias2[b * 512 + c2] = acc + pb[c2];
  }
}

__global__ __launch_bounds__(256) void k_gemm_fb(const unsigned short* __restrict__ mwbf,
    const float* __restrict__ x, const float* __restrict__ afac,
    const float* __restrict__ bias2, float* __restrict__ out) {
  __shared__ __align__(16) unsigned short Ab[128 * 32];
  __shared__ __align__(16) unsigned short Bb[128 * 32];
  __shared__ float Afs[512];
  int bid0 = blockIdx.x;
  int bid = (bid0 & 7) * 256 + (bid0 >> 3);
  int b = bid >> 7, rem = bid & 127, nt = rem >> 2, mt = rem & 3;
  int m0 = mt * 128, s0 = nt * 128;
  int t = threadIdx.x, w = t >> 6, l = t & 63;
  int wm = (w >> 1) * 64, wn = (w & 1) * 64;
  const unsigned short* Ag = mwbf + (size_t)m0 * CC;
  int lr = l >> 2, lk = (l & 3) * 8;
  int fr = l & 15, fk = (l >> 4) * 8;
  for (int i = t; i < 512; i += 256) Afs[i] = afac[b * CC + i];
  __syncthreads();
  f32x4 acc[4][4] = {};
  for (int k0 = 0; k0 < CC; k0 += 32) {
#pragma unroll
    for (int q = 0; q < 2; ++q) {
      int row = w * 32 + q * 16;
      gl_lds16(Ag + (size_t)(row + lr) * CC + k0 + lk, &Ab[row * 32]);
    }
#pragma unroll
    for (int i2 = 0; i2 < 4; ++i2) {
      int e = i2 * 256 + t;
      int row = e >> 5, f4 = e & 31;
      float4 v = *(const float4*)&x[((size_t)(b * CC + k0 + row)) * SS + s0 + f4 * 4];
      float a = Afs[k0 + row];
      Bb[(f4 * 4 + 0) * 32 + row] = f2bf(v.x * a);
      Bb[(f4 * 4 + 1) * 32 + row] = f2bf(v.y * a);
      Bb[(f4 * 4 + 2) * 32 + row] = f2bf(v.z * a);
      Bb[(f4 * 4 + 3) * 32 + row] = f2bf(v.w * a);
    }
    __syncthreads();
    bf16x8 af[4], bfr[4];
#pragma unroll
    for (int i = 0; i < 4; ++i) af[i] = *(const bf16x8*)&Ab[(wm + i * 16 + fr) * 32 + fk];
#pragma unroll
    for (int j = 0; j < 4; ++j) bfr[j] = *(const bf16x8*)&Bb[(wn + j * 16 + fr) * 32 + fk];
#pragma unroll
    for (int i = 0; i < 4; ++i)
#pragma unroll
      for (int j = 0; j < 4; ++j)
        acc[i][j] = __builtin_amdgcn_mfma_f32_16x16x32_bf16(af[i], bfr[j], acc[i][j], 0, 0, 0);
    __syncthreads();
  }
  int c2b = m0 + wm, sb = s0 + wn;
  float bi[4][4];
#pragma unroll
  for (int i = 0; i < 4; ++i)
#pragma unroll
    for (int r = 0; r < 4; ++r)
      bi[i][r] = bias2[b * CC + c2b + i * 16 + (l >> 4) * 4 + r];
#pragma unroll
  for (int i = 0; i < 4; ++i)
#pragma unroll
    for (int j = 0; j < 4; ++j)
#pragma unroll
      for (int r = 0; r < 4; ++r) {
        int c2 = c2b + i * 16 + (l >> 4) * 4 + r;
        int s = sb + j * 16 + (l & 15);
        size_t oi = ((size_t)(b * CC + c2)) * SS + s;
        out[oi] = acc[i][j][r] + bi[i][r] + x[oi];
      }
}

extern "C" void kernel_launch(void* const* d_in, const int* in_sizes, int n_in,
                              void* d_out, int out_size, void* d_ws, size_t ws_size,
                              hipStream_t stream) {
  const float* x = (const float*)d_in[0];
  const float* ng = (const float*)d_in[1];
  const float* nb = (const float*)d_in[2];
  const float* qw = (const float*)d_in[3];
  const float* qb = (const float*)d_in[4];
  const float* pw = (const float*)d_in[5];
  const float* pb = (const float*)d_in[6];
  float* out = (float*)d_out;
  char* ws = (char*)d_ws;

  float* part = (float*)(ws + 0);                          //   8 KB
  float* afac = (float*)(ws + 65536);                      //  32 KB (fb only)
  float* bcv = (float*)(ws + 98304);                       //  32 KB (fb only)
  float* bias2 = (float*)(ws + 131072);                    //  32 KB
  float* mw = (float*)(ws + 163840);                       //   1 MB
  unsigned short* mwbf = (unsigned short*)(ws + 1212416);  // 512 KB (fb only)
  unsigned short* mwa = (unsigned short*)(ws + 1736704);   //   8 MB (frag-ordered, fast)
  unsigned short* xbf = (unsigned short*)(ws + 10125312);  //  64 MB bf16(x) -> end 77234176

  bool fast = ws_size >= 77234176ull;

  if (fast) {
    k_cvt_lin<<<576, 256, 0, stream>>>(x, pw, qw, xbf, part, mw);
    k_prep<<<2176, 256, 0, stream>>>(part, ng, nb, mw, pw, qb, pb, mwa, bias2);
    k_fused10<<<1024, 512, 0, stream>>>(mwa, xbf, bias2, out);
  } else {
    k_stats<<<1024, 256, 0, stream>>>(x, part);
    k_mw<<<64, 256, 0, stream>>>(pw, qw, mw, mwbf);
    k_fin<<<16, 256, 0, stream>>>(part, ng, nb, afac, bcv, 8);
    k_bias2<<<128, 256, 0, stream>>>(mw, bcv, pw, qb, pb, bias2);
    k_gemm_fb<<<2048, 256, 0, stream>>>(mwbf, x, afac, bias2, out);
  }
}